// Round 11
// baseline (261.808 us; speedup 1.0000x reference)
//
#include <hip/hip_runtime.h>

#define NBINS 128
#define NB2   (NBINS * NBINS)
#define NBUCK 36              // 6x6 bands of 24 bins; tile = 32x32 at 24b-4
#define BAND  24
#define TILE0 (-4)
#define SORT_TPB  256
#define SORT_NBLK 256
#define GEMM_TPB  1024
#define GEMM_NBLK 256
#define NWAVES (GEMM_NBLK * (GEMM_TPB / 64))

// ws layout (u32 indices). ws[0] = done counter (0xAA-poison-aware).
#define WS_CNT  16                          // [256][36] per-block counts
#define WS_BASE (WS_CNT + SORT_NBLK * NBUCK)   // [256][36] scatter bases
#define WS_BST  (WS_BASE + SORT_NBLK * NBUCK)  // [37] bucket point offsets
#define WS_COFF (WS_BST + NBUCK + 1)           // [37] bucket chunk offsets
#define WS_SORT 18560                          // float2[n] sorted (u,v); 8B-aligned

typedef __attribute__((ext_vector_type(8)))  short short8;
typedef __attribute__((ext_vector_type(16))) float f32x16;

__device__ __forceinline__ unsigned pk_bf16(float a, float b) {
    const unsigned ar = __float_as_uint(a) + 0x8000u;   // round-half-up bf16
    const unsigned br = __float_as_uint(b) + 0x8000u;
    return __builtin_amdgcn_perm(br, ar, 0x07060302u);
}
#define WC (-0.72134752044448170f)   // -0.5*log2(e): w(d)=exp2(WC*d*d)

union S8 { short8 s; unsigned u[4]; };

__device__ __forceinline__ S8 gen_frag(const float4 a, const float4 b, float base) {
    float d0 = a.x - base, d1 = a.y - base, d2 = a.z - base, d3 = a.w - base;
    float d4 = b.x - base, d5 = b.y - base, d6 = b.z - base, d7 = b.w - base;
    const float w0 = __builtin_amdgcn_exp2f((WC * d0) * d0);
    const float w1 = __builtin_amdgcn_exp2f((WC * d1) * d1);
    const float w2 = __builtin_amdgcn_exp2f((WC * d2) * d2);
    const float w3 = __builtin_amdgcn_exp2f((WC * d3) * d3);
    const float w4 = __builtin_amdgcn_exp2f((WC * d4) * d4);
    const float w5 = __builtin_amdgcn_exp2f((WC * d5) * d5);
    const float w6 = __builtin_amdgcn_exp2f((WC * d6) * d6);
    const float w7 = __builtin_amdgcn_exp2f((WC * d7) * d7);
    S8 r;
    r.u[0] = pk_bf16(w0, w1); r.u[1] = pk_bf16(w2, w3);
    r.u[2] = pk_bf16(w4, w5); r.u[3] = pk_bf16(w6, w7);
    return r;
}

__device__ __forceinline__ int bucket_of(float u, float v) {
    const int bx = min(5, max(0, (int)floorf(u * (1.0f / BAND))));
    const int by = min(5, max(0, (int)floorf(v * (1.0f / BAND))));
    return bx * 6 + by;
}

// K1: per-block bucket counts (wave-aggregated: leader-only LDS atomics --
// contended multi-lane LDS atomics measured 3.3 cyc/lane in R3-R5, avoid).
__global__ __launch_bounds__(SORT_TPB) void count_kernel(
    const float* __restrict__ x, const float* __restrict__ ex,
    const float* __restrict__ ey, unsigned* __restrict__ ws, int n)
{
    __shared__ unsigned lcnt[NBUCK];
    const int tid = (int)threadIdx.x, lane = tid & 63;
    if (tid < NBUCK) lcnt[tid] = 0;
    __syncthreads();
    const float lox = ex[0], loy = ey[0];
    const float ibx = 1.0f / (ex[1] - ex[0]), iby = 1.0f / (ey[1] - ey[0]);
    const int stride = SORT_NBLK * SORT_TPB;
    for (int p = (int)blockIdx.x * SORT_TPB + tid; p < n; p += stride) {
        const float2 xy = *(const float2*)(x + (size_t)p * 6);
        const float u = (xy.x - lox) * ibx - 0.5f;
        const float v = (xy.y - loy) * iby - 0.5f;
        const int b = bucket_of(u, v);
        unsigned long long pend = __ballot(1);
        while (pend) {
            const int src = __ffsll(pend) - 1;
            const int bb = __shfl(b, src, 64);
            const unsigned long long m = __ballot(b == bb);
            if (lane == src) atomicAdd(&lcnt[bb], (unsigned)__popcll(m));
            pend &= ~m;
        }
    }
    __syncthreads();
    if (tid < NBUCK) ws[WS_CNT + (int)blockIdx.x * NBUCK + tid] = lcnt[tid];
}

// K2: single block -- column scans over per-block counts, bucket point
// offsets, chunk (64-pt) offsets, per-block scatter bases.
__global__ __launch_bounds__(64) void scan_kernel(unsigned* __restrict__ ws)
{
    __shared__ unsigned coltot[NBUCK];
    __shared__ unsigned bst[NBUCK + 1], cof[NBUCK + 1];
    const int t = (int)threadIdx.x;
    if (t < NBUCK) {
        unsigned run = 0;
        for (int blk = 0; blk < SORT_NBLK; ++blk) {
            const unsigned c = ws[WS_CNT + blk * NBUCK + t];
            ws[WS_BASE + blk * NBUCK + t] = run;   // local prefix
            run += c;
        }
        coltot[t] = run;
    }
    __syncthreads();
    if (t == 0) {
        unsigned s = 0, cs = 0;
        for (int b = 0; b < NBUCK; ++b) {
            bst[b] = s; cof[b] = cs;
            s += coltot[b]; cs += (coltot[b] + 63) >> 6;
        }
        bst[NBUCK] = s; cof[NBUCK] = cs;
    }
    __syncthreads();
    if (t < NBUCK + 1) { ws[WS_BST + t] = bst[t]; ws[WS_COFF + t] = cof[t]; }
    if (t < NBUCK) {
        const unsigned bs = bst[t];
        for (int blk = 0; blk < SORT_NBLK; ++blk)
            ws[WS_BASE + blk * NBUCK + t] += bs;
    }
}

// K3: scatter (u,v) into bucket-sorted float2 array. Slot = block base +
// leader-atomic group base + intra-wave rank (unique by construction).
__global__ __launch_bounds__(SORT_TPB) void scatter_kernel(
    const float* __restrict__ x, const float* __restrict__ ex,
    const float* __restrict__ ey, unsigned* __restrict__ ws,
    float2* __restrict__ sorted, int n)
{
    __shared__ unsigned lcnt[NBUCK];
    const int tid = (int)threadIdx.x, lane = tid & 63;
    if (tid < NBUCK) lcnt[tid] = ws[WS_BASE + (int)blockIdx.x * NBUCK + tid];
    __syncthreads();
    const float lox = ex[0], loy = ey[0];
    const float ibx = 1.0f / (ex[1] - ex[0]), iby = 1.0f / (ey[1] - ey[0]);
    const int stride = SORT_NBLK * SORT_TPB;
    for (int p = (int)blockIdx.x * SORT_TPB + tid; p < n; p += stride) {
        const float2 xy = *(const float2*)(x + (size_t)p * 6);
        const float u = (xy.x - lox) * ibx - 0.5f;
        const float v = (xy.y - loy) * iby - 0.5f;
        const int b = bucket_of(u, v);
        unsigned long long pend = __ballot(1);
        while (pend) {
            const int src = __ffsll(pend) - 1;
            const int bb = __shfl(b, src, 64);
            const unsigned long long m = __ballot(b == bb);
            unsigned old = 0;
            if (lane == src) old = atomicAdd(&lcnt[bb], (unsigned)__popcll(m));
            const unsigned base = __shfl(old, src, 64);
            if (b == bb) {
                const unsigned rank =
                    (unsigned)__popcll(m & ((1ull << lane) - 1ull));
                sorted[base + rank] = make_float2(u, v);
            }
            pend &= ~m;
        }
    }
}

// K4: per-bucket 32x32 tile GEMM. Each point's full +-4 window lies in its
// bucket tile (24+8=32). Per 16-pt k-step: 1 A-gen + 1 B-gen + 1 MFMA (vs 8
// gens dense -- R7-R10 proved dense is exp-issue-floor-limited at ~66us).
// Wave: grid-strided chunks; flush AGPR tile to out via predicated global
// atomics on bucket switch. Last-block finalize (R10-proven counter).
__global__ __launch_bounds__(GEMM_TPB, 4) void kde_gemm_kernel(
    const float2* __restrict__ sorted,
    const float* __restrict__ ex, const float* __restrict__ ey,
    float* __restrict__ out, unsigned* __restrict__ ws)
{
    __shared__ __align__(16) float u_s[16][64];
    __shared__ __align__(16) float v_s[16][64];
    __shared__ unsigned bstartS[NBUCK + 1], choffS[NBUCK + 1];
    __shared__ float redbuf[16];
    __shared__ int lastflag;

    const int tid  = (int)threadIdx.x;
    const int lane = tid & 63, half = lane >> 5, l31 = lane & 31;
    const int wave = tid >> 6;
    if (tid < NBUCK + 1) {
        bstartS[tid] = ws[WS_BST + tid];
        choffS[tid]  = ws[WS_COFF + tid];
    }
    __syncthreads();
    const unsigned nctot = choffS[NBUCK];

    f32x16 acc;
    #pragma unroll
    for (int r = 0; r < 16; ++r) acc[r] = 0.f;
    int curb = -1;

    auto flush = [&](int b) {
        const int rowbase = BAND * (b / 6) + TILE0;
        const int col     = BAND * (b % 6) + TILE0 + l31;
        const bool cok = (col >= 0) && (col < NBINS);
        #pragma unroll
        for (int r = 0; r < 16; ++r) {      // C/D layout verified R6-R10
            const int row = rowbase + (r & 3) + 8 * (r >> 2) + 4 * half;
            if (cok && row >= 0 && row < NBINS)
                unsafeAtomicAdd(&out[row * NBINS + col], acc[r]);
        }
        #pragma unroll
        for (int r = 0; r < 16; ++r) acc[r] = 0.f;
    };

    for (unsigned c = (unsigned)blockIdx.x * 16 + wave; c < nctot; c += NWAVES) {
        int b = 0;
        while (c >= choffS[b + 1]) ++b;     // wave-uniform, <=36 iters
        if (b != curb) { if (curb >= 0) flush(curb); curb = b; }

        const unsigned pstart = bstartS[b] + (c - choffS[b]) * 64;
        const unsigned pend_  = bstartS[b + 1];
        const unsigned idx = pstart + (unsigned)lane;
        float2 uv = make_float2(1e9f, 1e9f);   // pad -> weight 0
        if (idx < pend_) uv = sorted[idx];
        u_s[wave][lane] = uv.x; v_s[wave][lane] = uv.y;

        const float rbase = (float)(BAND * (b / 6) + TILE0 + l31);
        const float cbase = (float)(BAND * (b % 6) + TILE0 + l31);
        #pragma unroll
        for (int s4 = 0; s4 < 4; ++s4) {       // 4 k-steps of 16 points
            const int kb = s4 * 16 + half * 8;
            const float4 ua = *(const float4*)&u_s[wave][kb];
            const float4 ub = *(const float4*)&u_s[wave][kb + 4];
            const float4 va = *(const float4*)&v_s[wave][kb];
            const float4 vb = *(const float4*)&v_s[wave][kb + 4];
            const S8 af = gen_frag(ua, ub, rbase);
            const S8 bf = gen_frag(va, vb, cbase);
            acc = __builtin_amdgcn_mfma_f32_32x32x16_bf16(af.s, bf.s, acc, 0, 0, 0);
        }
    }
    if (curb >= 0) flush(curb);

    // ---- last-block finalize (counter at ws[0]: poison- or zero-start) ----
    __threadfence();
    __syncthreads();
    if (tid == 0) {
        const unsigned old = __hip_atomic_fetch_add(
            &ws[0], 1u, __ATOMIC_ACQ_REL, __HIP_MEMORY_SCOPE_AGENT);
        lastflag = (old == 0xAAAAAAAAu + (unsigned)(GEMM_NBLK - 1)) ||
                   (old == (unsigned)(GEMM_NBLK - 1));
    }
    __syncthreads();
    if (lastflag) {
        __threadfence();
        float4 vals[4];
        float s = 0.f;
        #pragma unroll
        for (int k = 0; k < 4; ++k) {
            vals[k] = ((const float4*)out)[tid + k * GEMM_TPB];
            s += vals[k].x + vals[k].y + vals[k].z + vals[k].w;
        }
        #pragma unroll
        for (int off = 32; off > 0; off >>= 1) s += __shfl_down(s, off, 64);
        if (lane == 0) redbuf[wave] = s;
        __syncthreads();
        float tot = 0.f;
        #pragma unroll
        for (int w = 0; w < 16; ++w) tot += redbuf[w];
        const float inv = 1.0f / (tot * (ex[1] - ex[0]) * (ey[1] - ey[0]));
        #pragma unroll
        for (int k = 0; k < 4; ++k) {
            float4 o = vals[k];
            o.x *= inv; o.y *= inv; o.z *= inv; o.w *= inv;
            ((float4*)out)[tid + k * GEMM_TPB] = o;
        }
    }
}

extern "C" void kernel_launch(void* const* d_in, const int* in_sizes, int n_in,
                              void* d_out, int out_size, void* d_ws, size_t ws_size,
                              hipStream_t stream)
{
    const float* x  = (const float*)d_in[0];
    const float* ex = (const float*)d_in[1];
    const float* ey = (const float*)d_in[2];
    float* out = (float*)d_out;
    const int n = in_sizes[0] / 6;

    unsigned* ws = (unsigned*)d_ws;
    float2* sorted = (float2*)((char*)d_ws + (size_t)WS_SORT * 4);
    // ws use: 74240 B tables + n*8 B sorted ~= 4.07 MB (<< 16.8 MB proven in R4)

    count_kernel<<<SORT_NBLK, SORT_TPB, 0, stream>>>(x, ex, ey, ws, n);
    scan_kernel<<<1, 64, 0, stream>>>(ws);
    scatter_kernel<<<SORT_NBLK, SORT_TPB, 0, stream>>>(x, ex, ey, ws, sorted, n);
    kde_gemm_kernel<<<GEMM_NBLK, GEMM_TPB, 0, stream>>>(sorted, ex, ey, out, ws);
}

// Round 12
// 181.085 us; speedup vs baseline: 1.4458x; 1.4458x over previous
//
#include <hip/hip_runtime.h>

#define NBINS 128
#define NB2   (NBINS * NBINS)
#define NBUCK 36              // 6x6 bands of 24 bins; tile 32x32 covers +-4
#define BAND  24
#define TILE0 (-4)
#define SORT_TPB  256
#define SORT_NBLK 256
#define GEMM_TPB  1024
#define GEMM_NBLK 256

// ws layout (u32 indices). ws[0] = done counter (0xAA-poison-aware).
#define WS_CNT  16                       // counts[256][36]
#define WS_SORT_BYTES 40960              // float2[n] sorted (u,v)

typedef __attribute__((ext_vector_type(8)))  short short8;
typedef __attribute__((ext_vector_type(16))) float f32x16;

__device__ __forceinline__ unsigned pk_bf16(float a, float b) {
    const unsigned ar = __float_as_uint(a) + 0x8000u;   // round-half-up bf16
    const unsigned br = __float_as_uint(b) + 0x8000u;
    return __builtin_amdgcn_perm(br, ar, 0x07060302u);
}
#define WC (-0.72134752044448170f)   // -0.5*log2(e): w(d)=exp2(WC*d*d)

union S8 { short8 s; unsigned u[4]; };

__device__ __forceinline__ S8 gen_frag(const float4 a, const float4 b, float base) {
    float d0 = a.x - base, d1 = a.y - base, d2 = a.z - base, d3 = a.w - base;
    float d4 = b.x - base, d5 = b.y - base, d6 = b.z - base, d7 = b.w - base;
    const float w0 = __builtin_amdgcn_exp2f((WC * d0) * d0);
    const float w1 = __builtin_amdgcn_exp2f((WC * d1) * d1);
    const float w2 = __builtin_amdgcn_exp2f((WC * d2) * d2);
    const float w3 = __builtin_amdgcn_exp2f((WC * d3) * d3);
    const float w4 = __builtin_amdgcn_exp2f((WC * d4) * d4);
    const float w5 = __builtin_amdgcn_exp2f((WC * d5) * d5);
    const float w6 = __builtin_amdgcn_exp2f((WC * d6) * d6);
    const float w7 = __builtin_amdgcn_exp2f((WC * d7) * d7);
    S8 r;
    r.u[0] = pk_bf16(w0, w1); r.u[1] = pk_bf16(w2, w3);
    r.u[2] = pk_bf16(w4, w5); r.u[3] = pk_bf16(w6, w7);
    return r;
}

__device__ __forceinline__ int bucket_of(float u, float v) {
    const int bx = min(5, max(0, (int)floorf(u * (1.0f / BAND))));
    const int by = min(5, max(0, (int)floorf(v * (1.0f / BAND))));
    return bx * 6 + by;
}

// K1: per-block bucket counts (ballot-aggregated leader-only LDS atomics).
__global__ __launch_bounds__(SORT_TPB) void count_kernel(
    const float* __restrict__ x, const float* __restrict__ ex,
    const float* __restrict__ ey, unsigned* __restrict__ ws, int n)
{
    __shared__ unsigned lcnt[NBUCK];
    const int tid = (int)threadIdx.x, lane = tid & 63;
    if (tid < NBUCK) lcnt[tid] = 0;
    __syncthreads();
    const float lox = ex[0], loy = ey[0];
    const float ibx = 1.0f / (ex[1] - ex[0]), iby = 1.0f / (ey[1] - ey[0]);
    const int stride = SORT_NBLK * SORT_TPB;
    for (int p = (int)blockIdx.x * SORT_TPB + tid; p < n; p += stride) {
        const float2 xy = *(const float2*)(x + (size_t)p * 6);
        const float u = (xy.x - lox) * ibx - 0.5f;
        const float v = (xy.y - loy) * iby - 0.5f;
        const int b = bucket_of(u, v);
        unsigned long long pend = __ballot(1);
        while (pend) {
            const int src = __ffsll(pend) - 1;
            const int bb = __shfl(b, src, 64);
            const unsigned long long m = __ballot(b == bb);
            if (lane == src) atomicAdd(&lcnt[bb], (unsigned)__popcll(m));
            pend &= ~m;
        }
    }
    __syncthreads();
    if (tid < NBUCK) ws[WS_CNT + (int)blockIdx.x * NBUCK + tid] = lcnt[tid];
}

// K2: scatter. Each block SELF-COMPUTES its scatter bases from the count
// table (R11's single-block serial-scan kernel was ~60-100us latency-bound;
// this is ~2us done in parallel by every block).
__global__ __launch_bounds__(SORT_TPB) void scatter_kernel(
    const float* __restrict__ x, const float* __restrict__ ex,
    const float* __restrict__ ey, unsigned* __restrict__ ws,
    float2* __restrict__ sorted, int n)
{
    __shared__ unsigned lcnt[NBUCK];     // cursors
    __shared__ unsigned pres[NBUCK], ctot[NBUCK], bst[NBUCK + 1];
    const int tid = (int)threadIdx.x, lane = tid & 63;
    if (tid < NBUCK) {
        unsigned run = 0, pr = 0;
        #pragma unroll 8
        for (int blk = 0; blk < SORT_NBLK; ++blk) {
            if (blk == (int)blockIdx.x) pr = run;
            run += ws[WS_CNT + blk * NBUCK + tid];
        }
        pres[tid] = pr; ctot[tid] = run;
    }
    __syncthreads();
    if (tid == 0) {
        unsigned s = 0;
        for (int b = 0; b < NBUCK; ++b) { bst[b] = s; s += ctot[b]; }
        bst[NBUCK] = s;
    }
    __syncthreads();
    if (tid < NBUCK) lcnt[tid] = bst[tid] + pres[tid];
    __syncthreads();

    const float lox = ex[0], loy = ey[0];
    const float ibx = 1.0f / (ex[1] - ex[0]), iby = 1.0f / (ey[1] - ey[0]);
    const int stride = SORT_NBLK * SORT_TPB;
    for (int p = (int)blockIdx.x * SORT_TPB + tid; p < n; p += stride) {
        const float2 xy = *(const float2*)(x + (size_t)p * 6);
        const float u = (xy.x - lox) * ibx - 0.5f;
        const float v = (xy.y - loy) * iby - 0.5f;
        const int b = bucket_of(u, v);
        unsigned long long pend = __ballot(1);
        while (pend) {
            const int src = __ffsll(pend) - 1;
            const int bb = __shfl(b, src, 64);
            const unsigned long long m = __ballot(b == bb);
            unsigned old = 0;
            if (lane == src) old = atomicAdd(&lcnt[bb], (unsigned)__popcll(m));
            const unsigned base = __shfl(old, src, 64);
            if (b == bb) {
                const unsigned rank =
                    (unsigned)__popcll(m & ((1ull << lane) - 1ull));
                sorted[base + rank] = make_float2(u, v);
            }
            pend &= ~m;
        }
    }
}

// K3: bucketed 32x32-tile GEMM. Block i owns the CONTIGUOUS chunk range
// [i*nctot/256,(i+1)*nctot/256); per bucket-segment all 16 waves cooperate,
// then 4 barrier-phases merge wave tiles into 4 LDS slots and ONE
// 1024-atomic flush per block-segment (~295 segments total; R11's per-wave
// flush was 9M contended atomics = 130us at 5.7% VALUBusy).
__global__ __launch_bounds__(GEMM_TPB) void kde_gemm_kernel(
    const float2* __restrict__ sorted,
    const float* __restrict__ ex, const float* __restrict__ ey,
    float* __restrict__ out, unsigned* __restrict__ ws)
{
    __shared__ __align__(16) float u_s[16][64];
    __shared__ __align__(16) float v_s[16][64];
    __shared__ float tileS[4][1024];                  // 16 KB merge slots
    __shared__ unsigned ctot[NBUCK], bstS[NBUCK + 1], cofS[NBUCK + 1];
    __shared__ float redbuf[16];
    __shared__ int lastflag;

    const int tid  = (int)threadIdx.x;
    const int lane = tid & 63, half = lane >> 5, l31 = lane & 31;
    const int wave = tid >> 6;

    if (tid < NBUCK) {
        unsigned run = 0;
        #pragma unroll 8
        for (int blk = 0; blk < SORT_NBLK; ++blk)
            run += ws[WS_CNT + blk * NBUCK + tid];
        ctot[tid] = run;
    }
    __syncthreads();
    if (tid == 0) {
        unsigned s = 0, cs = 0;
        for (int b = 0; b < NBUCK; ++b) {
            bstS[b] = s; cofS[b] = cs;
            s += ctot[b]; cs += (ctot[b] + 63) >> 6;
        }
        bstS[NBUCK] = s; cofS[NBUCK] = cs;
    }
    __syncthreads();
    const unsigned nctot = cofS[NBUCK];
    const unsigned c0 = ((unsigned)blockIdx.x * nctot) / GEMM_NBLK;
    const unsigned c1 = ((unsigned)(blockIdx.x + 1) * nctot) / GEMM_NBLK;

    if (c0 < c1) {
        int b = 0;
        while (cofS[b + 1] <= c0) ++b;
        for (; b < NBUCK && cofS[b] < c1; ++b) {
            const unsigned s0 = (c0 > cofS[b]) ? c0 : cofS[b];
            const unsigned s1 = (c1 < cofS[b + 1]) ? c1 : cofS[b + 1];
            if (s0 >= s1) continue;

            f32x16 acc;
            #pragma unroll
            for (int r = 0; r < 16; ++r) acc[r] = 0.f;

            const float rbase = (float)(BAND * (b / 6) + TILE0 + l31);
            const float cbase = (float)(BAND * (b % 6) + TILE0 + l31);
            const unsigned plim = bstS[b + 1];
            for (unsigned c = s0 + (unsigned)wave; c < s1; c += 16) {
                const unsigned pstart = bstS[b] + (c - cofS[b]) * 64;
                const unsigned idx = pstart + (unsigned)lane;
                float2 uv = make_float2(1e9f, 1e9f);   // pad -> weight 0
                if (idx < plim) uv = sorted[idx];
                u_s[wave][lane] = uv.x; v_s[wave][lane] = uv.y;
                #pragma unroll
                for (int s4 = 0; s4 < 4; ++s4) {
                    const int kb = s4 * 16 + half * 8;
                    const float4 ua = *(const float4*)&u_s[wave][kb];
                    const float4 ub = *(const float4*)&u_s[wave][kb + 4];
                    const float4 va = *(const float4*)&v_s[wave][kb];
                    const float4 vb = *(const float4*)&v_s[wave][kb + 4];
                    const S8 af = gen_frag(ua, ub, rbase);
                    const S8 bf = gen_frag(va, vb, cbase);
                    acc = __builtin_amdgcn_mfma_f32_32x32x16_bf16(
                        af.s, bf.s, acc, 0, 0, 0);
                }
            }

            // merge 16 waves -> 4 slots in 4 phases (C/D layout proven R6-R11)
            #pragma unroll
            for (int p = 0; p < 4; ++p) {
                __syncthreads();
                if ((wave >> 2) == p) {
                    float* slot = tileS[wave & 3];
                    #pragma unroll
                    for (int r = 0; r < 16; ++r) {
                        const int off =
                            ((r & 3) + 8 * (r >> 2) + 4 * half) * 32 + l31;
                        if (p == 0) slot[off] = acc[r];
                        else        slot[off] += acc[r];
                    }
                }
            }
            __syncthreads();
            // one flush per block-segment: 1024 predicated global atomics
            {
                const int rit = tid >> 5, cit = tid & 31;
                const int row = BAND * (b / 6) + TILE0 + rit;
                const int col = BAND * (b % 6) + TILE0 + cit;
                const float val = tileS[0][tid] + tileS[1][tid] +
                                  tileS[2][tid] + tileS[3][tid];
                if (row >= 0 && row < NBINS && col >= 0 && col < NBINS)
                    unsafeAtomicAdd(&out[row * NBINS + col], val);
            }
            __syncthreads();     // slots reusable next segment
        }
    }

    // ---- last-block finalize (ws[0] counter: poison- or zero-start) ----
    __threadfence();
    __syncthreads();
    if (tid == 0) {
        const unsigned old = __hip_atomic_fetch_add(
            &ws[0], 1u, __ATOMIC_ACQ_REL, __HIP_MEMORY_SCOPE_AGENT);
        lastflag = (old == 0xAAAAAAAAu + (unsigned)(GEMM_NBLK - 1)) ||
                   (old == (unsigned)(GEMM_NBLK - 1));
    }
    __syncthreads();
    if (lastflag) {
        __threadfence();
        float4 vals[4];
        float s = 0.f;
        #pragma unroll
        for (int k = 0; k < 4; ++k) {
            vals[k] = ((const float4*)out)[tid + k * GEMM_TPB];
            s += vals[k].x + vals[k].y + vals[k].z + vals[k].w;
        }
        #pragma unroll
        for (int off = 32; off > 0; off >>= 1) s += __shfl_down(s, off, 64);
        if (lane == 0) redbuf[wave] = s;
        __syncthreads();
        float tot = 0.f;
        #pragma unroll
        for (int w = 0; w < 16; ++w) tot += redbuf[w];
        const float inv = 1.0f / (tot * (ex[1] - ex[0]) * (ey[1] - ey[0]));
        #pragma unroll
        for (int k = 0; k < 4; ++k) {
            float4 o = vals[k];
            o.x *= inv; o.y *= inv; o.z *= inv; o.w *= inv;
            ((float4*)out)[tid + k * GEMM_TPB] = o;
        }
    }
}

extern "C" void kernel_launch(void* const* d_in, const int* in_sizes, int n_in,
                              void* d_out, int out_size, void* d_ws, size_t ws_size,
                              hipStream_t stream)
{
    const float* x  = (const float*)d_in[0];
    const float* ex = (const float*)d_in[1];
    const float* ey = (const float*)d_in[2];
    float* out = (float*)d_out;
    const int n = in_sizes[0] / 6;

    unsigned* ws = (unsigned*)d_ws;
    float2* sorted = (float2*)((char*)d_ws + WS_SORT_BYTES);
    // ws use: ~40KB tables + n*8B sorted ~= 4.04MB (16.8MB capacity proven R4)

    count_kernel<<<SORT_NBLK, SORT_TPB, 0, stream>>>(x, ex, ey, ws, n);
    scatter_kernel<<<SORT_NBLK, SORT_TPB, 0, stream>>>(x, ex, ey, ws, sorted, n);
    kde_gemm_kernel<<<GEMM_NBLK, GEMM_TPB, 0, stream>>>(sorted, ex, ey, out, ws);
}